// Round 1
// 173.238 us; speedup vs baseline: 1.0094x; 1.0094x over previous
//
#include <hip/hip_runtime.h>
#include <hip/hip_bf16.h>

// TwoHotEmbedding: out[t] = w[i1[t]] + w[i2[t]], except out[t] = w[i1[t]] when i1==i2.
// One 64-lane wave handles TOK_PER_WAVE tokens. Per token, lane i moves one
// float4 (16 B): 64 lanes x 16 B = one full 256-float row, coalesced.
//
// This revision: TOK_PER_WAVE 8 -> 12. Theory: kernel dispatch (<61 us per
// rocprof top-k exclusion) sits ~1.7x above the ~30 us HBM floor; if the gap
// is memory-latency, +50% in-flight gather bytes per wave (16 KB -> 24 KB,
// still 4 waves/SIMD at ~112-120 VGPR, capped by __launch_bounds__(256,4))
// should cut it. If neutral, we are HBM random-access-efficiency bound.
// Output uses nontemporal stores so the 67 MB write-once stream doesn't
// evict gather rows from L2/L3.

#define EMBED_DIM 256
#define TOK_PER_WAVE 12

// clang native vector type — required by __builtin_nontemporal_store
// (HIP's float4 is a class and is rejected).
typedef float vf4 __attribute__((ext_vector_type(4)));

template <int N>
__device__ __forceinline__ void process_tokens(
    const int* __restrict__ idx1,
    const int* __restrict__ idx2,
    const float* __restrict__ weight,
    float* __restrict__ out,
    int t0, int lane)
{
    // t0 is wave-uniform (readfirstlane'd by caller) -> these become s_loads.
    int a[N], b[N];
#pragma unroll
    for (int i = 0; i < N; ++i) {
        a[i] = idx1[t0 + i];
        b[i] = idx2[t0 + i];
    }

    // Issue all 2N gather loads before consuming any (max MLP).
    vf4 va[N], vb[N];
#pragma unroll
    for (int i = 0; i < N; ++i) {
        va[i] = ((const vf4*)(weight + (size_t)a[i] * EMBED_DIM))[lane];
        vb[i] = ((const vf4*)(weight + (size_t)b[i] * EMBED_DIM))[lane];
    }

#pragma unroll
    for (int i = 0; i < N; ++i) {
        vf4 r = (a[i] == b[i]) ? va[i]            // scatter-to-same-slot sets 1, not 2
                               : (va[i] + vb[i]);
        vf4* dst = (vf4*)(out + (size_t)(t0 + i) * EMBED_DIM) + lane;
        __builtin_nontemporal_store(r, dst);
    }
}

__global__ __launch_bounds__(256, 4) void TwoHotEmbedding_13030930776069_kernel(
    const int* __restrict__ idx1,
    const int* __restrict__ idx2,
    const float* __restrict__ weight,
    float* __restrict__ out,
    int n_tokens)
{
    const int lane   = threadIdx.x & 63;
    const int waveId = (blockIdx.x * blockDim.x + threadIdx.x) >> 6;
    // t0 is wave-uniform; readfirstlane makes that provable -> scalar idx loads.
    const int t0 = __builtin_amdgcn_readfirstlane(waveId * TOK_PER_WAVE);
    if (t0 >= n_tokens) return;

    if (t0 + TOK_PER_WAVE <= n_tokens) {
        // Hot path: full batch, all loads issued back-to-back.
        process_tokens<TOK_PER_WAVE>(idx1, idx2, weight, out, t0, lane);
    } else {
        // Tail: at most one wave in the grid takes this path.
        const int nt = n_tokens - t0;
        for (int i = 0; i < nt; ++i) {
            int ai = idx1[t0 + i];
            int bi = idx2[t0 + i];
            vf4 va = ((const vf4*)(weight + (size_t)ai * EMBED_DIM))[lane];
            vf4 vb = ((const vf4*)(weight + (size_t)bi * EMBED_DIM))[lane];
            vf4 r = (ai == bi) ? va : (va + vb);
            vf4* dst = (vf4*)(out + (size_t)(t0 + i) * EMBED_DIM) + lane;
            __builtin_nontemporal_store(r, dst);
        }
    }
}

extern "C" void kernel_launch(void* const* d_in, const int* in_sizes, int n_in,
                              void* d_out, int out_size, void* d_ws, size_t ws_size,
                              hipStream_t stream) {
    const int*   idx1   = (const int*)d_in[0];    // input_one [16,4096] int32
    const int*   idx2   = (const int*)d_in[1];    // input_two [16,4096] int32
    const float* weight = (const float*)d_in[2];  // [100000,256] fp32
    float*       out    = (float*)d_out;          // [16,4096,256] fp32

    const int n_tokens = in_sizes[0];             // 65536
    // 4 waves/block x 12 tokens/wave = 48 tokens per 256-thread block
    const int tokens_per_block = 4 * TOK_PER_WAVE;
    const int blocks = (n_tokens + tokens_per_block - 1) / tokens_per_block;
    TwoHotEmbedding_13030930776069_kernel<<<blocks, 256, 0, stream>>>(
        idx1, idx2, weight, out, n_tokens);
}